// Round 2
// baseline (6477.201 us; speedup 1.0000x reference)
//
#include <hip/hip_runtime.h>
#include <math.h>

#define DEPTH 18
#define NNODES ((1 << DEPTH) - 1)

typedef unsigned short bf16raw;

__device__ __forceinline__ float sigm(float x) { return 1.0f / (1.0f + __expf(-x)); }

__device__ __forceinline__ float bf2f(bf16raw u) {
    union { unsigned int i; float f; } v;
    v.i = ((unsigned int)u) << 16;
    return v.f;
}
__device__ __forceinline__ bf16raw f2bf(float f) {
    union { float f; unsigned int i; } v;
    v.f = f;
    unsigned int r = v.i + 0x7FFFu + ((v.i >> 16) & 1u);  // round-to-nearest-even
    return (bf16raw)(r >> 16);
}

// ---------------------------------------------------------------------------
// k1_linear: G[m][col] for col in [0, S), S = 640 (non-leaf) or 384 (leaf).
// col = grp*128 + j, grp: 0=i, 1=o, 2=u, 3=f(child1), 4=f(child2)
// G = x . WA[grp]^T + a2 . WB[grp]^T + bA[grp] + bB[grp]
//   a2 = h_sum (grp<3), child1 h (grp==3), child2 h (grp==4); zero at leaf.
// h_all is bf16 raw. Tile: BM=128, BN=64, K-tiles 32; 256 thr, 8x4/thread.
// ---------------------------------------------------------------------------
__global__ __launch_bounds__(256, 2) void k1_linear(
    const float* __restrict__ embeds, const int* __restrict__ words,
    const bf16raw* __restrict__ h_all,
    const float* __restrict__ Wix, const float* __restrict__ bix,
    const float* __restrict__ Wih, const float* __restrict__ bih,
    const float* __restrict__ Wfx, const float* __restrict__ bfx,
    const float* __restrict__ Wfh, const float* __restrict__ bfh,
    const float* __restrict__ Wox, const float* __restrict__ box_,
    const float* __restrict__ Woh, const float* __restrict__ boh,
    const float* __restrict__ Wux, const float* __restrict__ bux,
    const float* __restrict__ Wuh, const float* __restrict__ buh,
    float* __restrict__ G, int off, int m0, int nm, int S, int leaf)
{
    __shared__ float sxT[32][132];   // [k][m]
    __shared__ float sa2T[32][132];
    __shared__ float sWAT[32][68];   // [k][j]
    __shared__ float sWBT[32][68];

    const int t = threadIdx.x;
    const int jt = blockIdx.x * 64;
    const int grp = jt >> 7;
    const int j0 = jt & 127;
    const int mbase = blockIdx.y * 128;

    const float *WA, *WB, *bA, *bB;
    switch (grp) {
        case 0:  WA = Wix; WB = Wih; bA = bix;  bB = bih; break;
        case 1:  WA = Wox; WB = Woh; bA = box_; bB = boh; break;
        case 2:  WA = Wux; WB = Wuh; bA = bux;  bB = buh; break;
        default: WA = Wfx; WB = Wfh; bA = bfx;  bB = bfh; break;
    }

    // loader: 2 threads per node-row, 16 k each
    const int lm = t >> 1;
    const int lk = (t & 1) * 16;
    const int m_l = mbase + lm;
    const bool mvalid = (m_l < nm);
    const long gl = (long)off + m0 + m_l;
    const float* xrow = nullptr;
    const bf16raw* h1row = nullptr;
    const bf16raw* h2row = nullptr;
    if (mvalid) {
        xrow = embeds + (long)words[gl] * 128;
        if (!leaf) {
            h1row = h_all + (2 * gl + 1) * 128;
            h2row = h_all + (2 * gl + 2) * 128;
        }
    }
    // weight loader: 4 threads per weight row, 8 k each
    const int wj = t >> 2;
    const int wk = (t & 3) * 8;

    const int tx = t & 15;   // cols j = tx*4 .. +3
    const int ty = t >> 4;   // rows m = ty*8 .. +7

    float acc[8][4];
#pragma unroll
    for (int i = 0; i < 8; i++)
#pragma unroll
        for (int j = 0; j < 4; j++) acc[i][j] = 0.f;

    for (int kt = 0; kt < 128; kt += 32) {
        __syncthreads();
#pragma unroll
        for (int q = 0; q < 4; q++) {
            const int kk = lk + q * 4;
            float4 xv = make_float4(0.f, 0.f, 0.f, 0.f);
            float a0 = 0.f, a1 = 0.f, a2v = 0.f, a3 = 0.f;
            if (mvalid) {
                xv = *(const float4*)(xrow + kt + kk);
                if (!leaf) {
                    if (grp < 3) {
                        ushort4 u1 = *(const ushort4*)(h1row + kt + kk);
                        ushort4 u2 = *(const ushort4*)(h2row + kt + kk);
                        a0 = bf2f(u1.x) + bf2f(u2.x);
                        a1 = bf2f(u1.y) + bf2f(u2.y);
                        a2v = bf2f(u1.z) + bf2f(u2.z);
                        a3 = bf2f(u1.w) + bf2f(u2.w);
                    } else {
                        const bf16raw* hr = (grp == 3) ? h1row : h2row;
                        ushort4 u = *(const ushort4*)(hr + kt + kk);
                        a0 = bf2f(u.x); a1 = bf2f(u.y);
                        a2v = bf2f(u.z); a3 = bf2f(u.w);
                    }
                }
            }
            sxT[kk + 0][lm] = xv.x; sxT[kk + 1][lm] = xv.y;
            sxT[kk + 2][lm] = xv.z; sxT[kk + 3][lm] = xv.w;
            sa2T[kk + 0][lm] = a0; sa2T[kk + 1][lm] = a1;
            sa2T[kk + 2][lm] = a2v; sa2T[kk + 3][lm] = a3;
        }
#pragma unroll
        for (int q = 0; q < 2; q++) {
            const int kk = wk + q * 4;
            float4 wa = *(const float4*)(WA + (j0 + wj) * 128 + kt + kk);
            float4 wb = *(const float4*)(WB + (j0 + wj) * 128 + kt + kk);
            sWAT[kk + 0][wj] = wa.x; sWAT[kk + 1][wj] = wa.y;
            sWAT[kk + 2][wj] = wa.z; sWAT[kk + 3][wj] = wa.w;
            sWBT[kk + 0][wj] = wb.x; sWBT[kk + 1][wj] = wb.y;
            sWBT[kk + 2][wj] = wb.z; sWBT[kk + 3][wj] = wb.w;
        }
        __syncthreads();
#pragma unroll
        for (int k = 0; k < 32; k++) {
            float4 x0 = *(const float4*)&sxT[k][ty * 8];
            float4 x1 = *(const float4*)&sxT[k][ty * 8 + 4];
            float4 a0 = *(const float4*)&sa2T[k][ty * 8];
            float4 a1 = *(const float4*)&sa2T[k][ty * 8 + 4];
            float4 wa = *(const float4*)&sWAT[k][tx * 4];
            float4 wb = *(const float4*)&sWBT[k][tx * 4];
            float xm[8] = {x0.x, x0.y, x0.z, x0.w, x1.x, x1.y, x1.z, x1.w};
            float am[8] = {a0.x, a0.y, a0.z, a0.w, a1.x, a1.y, a1.z, a1.w};
            float wav[4] = {wa.x, wa.y, wa.z, wa.w};
            float wbv[4] = {wb.x, wb.y, wb.z, wb.w};
#pragma unroll
            for (int mi = 0; mi < 8; mi++)
#pragma unroll
                for (int ji = 0; ji < 4; ji++)
                    acc[mi][ji] += xm[mi] * wav[ji] + am[mi] * wbv[ji];
        }
    }

    float bias[4];
#pragma unroll
    for (int ji = 0; ji < 4; ji++)
        bias[ji] = bA[j0 + tx * 4 + ji] + bB[j0 + tx * 4 + ji];
#pragma unroll
    for (int mi = 0; mi < 8; mi++) {
        const int m = mbase + ty * 8 + mi;
        if (m < nm) {
            float4 v = make_float4(acc[mi][0] + bias[0], acc[mi][1] + bias[1],
                                   acc[mi][2] + bias[2], acc[mi][3] + bias[3]);
            *(float4*)(G + (long)m * S + jt + tx * 4) = v;
        }
    }
}

// ---------------------------------------------------------------------------
// k2_gates: one block (128 threads) per node. Gates, c/h update (bf16 store),
// fused logits + log_softmax + loss. Root writes logp to out[0..4].
// ---------------------------------------------------------------------------
__global__ __launch_bounds__(128) void k2_gates(
    const float* __restrict__ G,
    bf16raw* __restrict__ h_all, bf16raw* __restrict__ c_all,
    const int* __restrict__ labels,
    const float* __restrict__ Wout, const float* __restrict__ bout,
    float* __restrict__ partials, float* __restrict__ out,
    int off, int m0, int S, int leaf, int isroot)
{
    const int m = blockIdx.x;
    const int j = threadIdx.x;
    const long g = (long)off + m0 + m;
    const float* Grow = G + (long)m * S;

    float iv = sigm(Grow[j]);
    float ov = sigm(Grow[128 + j]);
    float uv = tanhf(Grow[256 + j]);
    float c = iv * uv;
    if (!leaf) {
        float f1 = sigm(Grow[384 + j]);
        float f2 = sigm(Grow[512 + j]);
        c += f1 * bf2f(c_all[(2 * g + 1) * 128 + j])
           + f2 * bf2f(c_all[(2 * g + 2) * 128 + j]);
    }
    float h = ov * tanhf(c);
    h_all[g * 128 + j] = f2bf(h);
    c_all[g * 128 + j] = f2bf(c);

    float p0 = h * Wout[j];
    float p1 = h * Wout[128 + j];
    float p2 = h * Wout[256 + j];
    float p3 = h * Wout[384 + j];
    float p4 = h * Wout[512 + j];
#pragma unroll
    for (int s = 32; s > 0; s >>= 1) {
        p0 += __shfl_down(p0, s);
        p1 += __shfl_down(p1, s);
        p2 += __shfl_down(p2, s);
        p3 += __shfl_down(p3, s);
        p4 += __shfl_down(p4, s);
    }
    __shared__ float red[2][5];
    if ((j & 63) == 0) {
        int w = j >> 6;
        red[w][0] = p0; red[w][1] = p1; red[w][2] = p2; red[w][3] = p3; red[w][4] = p4;
    }
    __syncthreads();
    if (j == 0) {
        float lg[5];
        float mx = -1e30f;
#pragma unroll
        for (int l = 0; l < 5; l++) {
            lg[l] = red[0][l] + red[1][l] + bout[l];
            mx = fmaxf(mx, lg[l]);
        }
        float se = 0.f;
#pragma unroll
        for (int l = 0; l < 5; l++) se += __expf(lg[l] - mx);
        float lse = __logf(se) + mx;
        int lab = labels[g];
        atomicAdd(&partials[m & 1023], lse - lg[lab]);
        if (isroot) {
#pragma unroll
            for (int l = 0; l < 5; l++) out[l] = lg[l] - lse;
        }
    }
}

__global__ __launch_bounds__(256) void k3_reduce(const float* __restrict__ partials,
                                                 float* __restrict__ out)
{
    const int t = threadIdx.x;
    float s = 0.f;
    for (int i = t; i < 1024; i += 256) s += partials[i];
#pragma unroll
    for (int d = 32; d > 0; d >>= 1) s += __shfl_down(s, d);
    __shared__ float red[4];
    if ((t & 63) == 0) red[t >> 6] = s;
    __syncthreads();
    if (t == 0) out[5] = red[0] + red[1] + red[2] + red[3];
}

// ---------------------------------------------------------------------------
extern "C" void kernel_launch(void* const* d_in, const int* in_sizes, int n_in,
                              void* d_out, int out_size, void* d_ws, size_t ws_size,
                              hipStream_t stream)
{
    const float* embeds = (const float*)d_in[0];
    const int* words = (const int*)d_in[1];
    const int* labels = (const int*)d_in[2];
    const float* Wix = (const float*)d_in[5],  *bix  = (const float*)d_in[6];
    const float* Wih = (const float*)d_in[7],  *bih  = (const float*)d_in[8];
    const float* Wfx = (const float*)d_in[9],  *bfx  = (const float*)d_in[10];
    const float* Wfh = (const float*)d_in[11], *bfh  = (const float*)d_in[12];
    const float* Wox = (const float*)d_in[13], *box_ = (const float*)d_in[14];
    const float* Woh = (const float*)d_in[15], *boh  = (const float*)d_in[16];
    const float* Wux = (const float*)d_in[17], *bux  = (const float*)d_in[18];
    const float* Wuh = (const float*)d_in[19], *buh  = (const float*)d_in[20];
    const float* Wout = (const float*)d_in[21], *bout = (const float*)d_in[22];
    float* out = (float*)d_out;

    // Workspace layout (bf16 h/c trees keep the fixed footprint at ~134 MB):
    //   h_all : NNODES*128 bf16  (67.1 MB)
    //   c_all : NNODES*128 bf16  (67.1 MB)
    //   partials : 1024 fp32     (4 KB)
    //   G : chunk*640 fp32       (sized from remaining ws)
    char* ws = (char*)d_ws;
    const size_t treeElems = (size_t)NNODES * 128;
    bf16raw* h_all = (bf16raw*)ws;
    bf16raw* c_all = h_all + treeElems;
    float* partials = (float*)(c_all + treeElems);
    float* G = partials + 1024;

    const size_t fixedBytes = 2 * treeElems * sizeof(bf16raw) + 1024 * sizeof(float);
    size_t avail = (ws_size > fixedBytes) ? (ws_size - fixedBytes) : 0;
    long cap = (long)(avail / (640 * sizeof(float)));
    int chunk = (int)((cap / 128) * 128);
    if (chunk < 128) chunk = 128;
    if (chunk > 131072) chunk = 131072;

    hipMemsetAsync(partials, 0, 1024 * sizeof(float), stream);

    for (int l = DEPTH - 1; l >= 0; --l) {
        const int n = 1 << l;
        const int off = n - 1;
        const int leaf = (l == DEPTH - 1) ? 1 : 0;
        const int S = leaf ? 384 : 640;
        for (int m0 = 0; m0 < n; m0 += chunk) {
            const int nm = (n - m0 < chunk) ? (n - m0) : chunk;
            dim3 g1(S / 64, (nm + 127) / 128);
            k1_linear<<<g1, 256, 0, stream>>>(embeds, words, h_all,
                Wix, bix, Wih, bih, Wfx, bfx, Wfh, bfh,
                Wox, box_, Woh, boh, Wux, bux, Wuh, buh,
                G, off, m0, nm, S, leaf);
            k2_gates<<<nm, 128, 0, stream>>>(G, h_all, c_all, labels, Wout, bout,
                partials, out, off, m0, S, leaf, (l == 0) ? 1 : 0);
        }
    }
    k3_reduce<<<1, 256, 0, stream>>>(partials, out);
}

// Round 3
// 836.917 us; speedup vs baseline: 7.7394x; 7.7394x over previous
//
#include <hip/hip_runtime.h>
#include <math.h>

#define DEPTH 18
#define NNODES ((1 << DEPTH) - 1)
#define NVOCAB 50000

typedef unsigned short bf16raw;
typedef __bf16 bf16x8 __attribute__((ext_vector_type(8)));
typedef float f32x4 __attribute__((ext_vector_type(4)));
typedef short short8 __attribute__((ext_vector_type(8)));

__device__ __forceinline__ float sigm(float x) { return 1.0f / (1.0f + __expf(-x)); }

__device__ __forceinline__ float bf2f(bf16raw u) {
    union { unsigned int i; float f; } v;
    v.i = ((unsigned int)u) << 16;
    return v.f;
}
__device__ __forceinline__ bf16raw f2bf(float f) {
    union { float f; unsigned int i; } v;
    v.f = f;
    unsigned int r = v.i + 0x7FFFu + ((v.i >> 16) & 1u);  // RNE
    return (bf16raw)(r >> 16);
}

// ---------------------------------------------------------------------------
// prep: fp32 embeds -> bf16 table
// ---------------------------------------------------------------------------
__global__ __launch_bounds__(256) void k_prep_embeds(const float* __restrict__ src,
                                                     bf16raw* __restrict__ dst, int n4)
{
    int i = blockIdx.x * blockDim.x + threadIdx.x;
    if (i < n4) {
        float4 v = ((const float4*)src)[i];
        ushort4 o;
        o.x = f2bf(v.x); o.y = f2bf(v.y); o.z = f2bf(v.z); o.w = f2bf(v.w);
        ((ushort4*)dst)[i] = o;
    }
}

// ---------------------------------------------------------------------------
// prep: BcatT[col 0..639][k 0..383] bf16  (col = grp*128+jj)
//  k 0-127   : Wx[jj][k]          (grp->{Wix,Wox,Wux,Wfx,Wfx})
//  k 128-255 : Wh[jj][k-128] for grp<4 (i,o,u,f1), 0 for f2
//  k 256-383 : Wh[jj][k-256] for grp<3 or grp==4 (f2), 0 for f1
// bias_cat[col] = bx[jj] + bh[jj]
// ---------------------------------------------------------------------------
__global__ __launch_bounds__(128) void k_prep_bcat(
    const float* __restrict__ Wix, const float* __restrict__ bix,
    const float* __restrict__ Wih, const float* __restrict__ bih,
    const float* __restrict__ Wfx, const float* __restrict__ bfx,
    const float* __restrict__ Wfh, const float* __restrict__ bfh,
    const float* __restrict__ Wox, const float* __restrict__ box_,
    const float* __restrict__ Woh, const float* __restrict__ boh,
    const float* __restrict__ Wux, const float* __restrict__ bux,
    const float* __restrict__ Wuh, const float* __restrict__ buh,
    bf16raw* __restrict__ BcatT, float* __restrict__ bias_cat)
{
    const int j = blockIdx.x;        // 0..639
    const int grp = j >> 7, jj = j & 127;
    const float *Wx, *Wh, *bx, *bh;
    switch (grp) {
        case 0: Wx = Wix; Wh = Wih; bx = bix;  bh = bih; break;
        case 1: Wx = Wox; Wh = Woh; bx = box_; bh = boh; break;
        case 2: Wx = Wux; Wh = Wuh; bx = bux;  bh = buh; break;
        default: Wx = Wfx; Wh = Wfh; bx = bfx; bh = bfh; break;
    }
    for (int k = threadIdx.x; k < 384; k += blockDim.x) {
        float v;
        if (k < 128) {
            v = Wx[jj * 128 + k];
        } else if (k < 256) {
            v = (grp == 4) ? 0.f : Wh[jj * 128 + (k - 128)];
        } else {
            v = (grp == 3) ? 0.f : Wh[jj * 128 + (k - 256)];
        }
        BcatT[(long)j * 384 + k] = f2bf(v);
    }
    if (threadIdx.x == 0) bias_cat[j] = bx[jj] + bh[jj];
}

// ---------------------------------------------------------------------------
// k_gemm: G[m][col] (bf16) = [x | h1 | h2] . BcatT^T + bias
// Block: 128 rows x 128 cols; 4 waves, each 64x64 = 4x4 frags of 16x16x32.
// Kc = 384 (nonleaf) / 128 (leaf, x only). ldG = 640 / 384.
// ---------------------------------------------------------------------------
__global__ __launch_bounds__(256) void k_gemm(
    const bf16raw* __restrict__ embeds_bf, const int* __restrict__ words,
    const bf16raw* __restrict__ h_all,
    const bf16raw* __restrict__ BcatT, const float* __restrict__ bias_cat,
    bf16raw* __restrict__ G, int off, int m0, int nm, int Kc, int ldG)
{
    __shared__ __align__(16) bf16raw sA[128 * 40];   // [row][k] pitch 40
    __shared__ __align__(16) bf16raw sB[128 * 40];   // [col][k] pitch 40

    const int t = threadIdx.x;
    const int mbase = blockIdx.x * 128;
    const int cb = blockIdx.y;

    // staging: 2 threads per row/col, 16 elems (32 B) each
    const int srow = t >> 1;
    const int shalf = (t & 1) * 16;

    const long glr = (long)off + m0 + mbase + srow;   // safe: < NNODES for all levels
    const bf16raw* ax  = embeds_bf + (long)words[glr] * 128;
    const bf16raw* ah1 = h_all + (2 * glr + 1) * 128;
    const bf16raw* ah2 = h_all + (2 * glr + 2) * 128;
    const bf16raw* bsrc = BcatT + ((long)cb * 128 + srow) * 384;

    const int lane = t & 63;
    const int w = t >> 6;
    const int wrow = (w >> 1) * 64;
    const int wcol = (w & 1) * 64;
    const int lrow = lane & 15;
    const int lquad = lane >> 4;
    const int lkoff = lquad * 8;

    f32x4 acc[4][4];
#pragma unroll
    for (int i = 0; i < 4; i++)
#pragma unroll
        for (int j = 0; j < 4; j++) acc[i][j] = (f32x4){0.f, 0.f, 0.f, 0.f};

    for (int kt = 0; kt < Kc; kt += 32) {
        const bf16raw* asrc = (kt < 128) ? ax : ((kt < 256) ? ah1 : ah2);
        const int kl = kt & 127;
        // hoist global loads above the barrier
        short8 av0 = *(const short8*)(asrc + kl + shalf);
        short8 av1 = *(const short8*)(asrc + kl + shalf + 8);
        short8 bv0 = *(const short8*)(bsrc + kt + shalf);
        short8 bv1 = *(const short8*)(bsrc + kt + shalf + 8);
        __syncthreads();   // protect previous iteration's frag reads
        *(short8*)&sA[srow * 40 + shalf] = av0;
        *(short8*)&sA[srow * 40 + shalf + 8] = av1;
        *(short8*)&sB[srow * 40 + shalf] = bv0;
        *(short8*)&sB[srow * 40 + shalf + 8] = bv1;
        __syncthreads();
        bf16x8 af[4], bfr[4];
#pragma unroll
        for (int i = 0; i < 4; i++) {
            af[i]  = *(const bf16x8*)&sA[(wrow + i * 16 + lrow) * 40 + lkoff];
            bfr[i] = *(const bf16x8*)&sB[(wcol + i * 16 + lrow) * 40 + lkoff];
        }
#pragma unroll
        for (int i = 0; i < 4; i++)
#pragma unroll
            for (int j = 0; j < 4; j++)
                acc[i][j] = __builtin_amdgcn_mfma_f32_16x16x32_bf16(af[i], bfr[j], acc[i][j], 0, 0, 0);
    }

    // epilogue: C/D layout col=lane&15, row=quad*4+reg (m89-verified)
#pragma unroll
    for (int j = 0; j < 4; j++) {
        const int col = cb * 128 + wcol + j * 16 + lrow;
        const float bias = bias_cat[col];
#pragma unroll
        for (int i = 0; i < 4; i++) {
            const int rbase = mbase + wrow + i * 16 + lquad * 4;
#pragma unroll
            for (int r = 0; r < 4; r++) {
                const int m = rbase + r;
                if (m < nm) G[(long)m * ldG + col] = f2bf(acc[i][j][r] + bias);
            }
        }
    }
}

// ---------------------------------------------------------------------------
// k_gates: one block (128 threads) per node. Gates, c/h update (bf16),
// fused logits + log_softmax + loss. Root writes logp to out[0..4].
// ---------------------------------------------------------------------------
__global__ __launch_bounds__(128) void k_gates(
    const bf16raw* __restrict__ G, int ldG,
    bf16raw* __restrict__ h_all, bf16raw* __restrict__ c_all,
    const int* __restrict__ labels,
    const float* __restrict__ Wout, const float* __restrict__ bout,
    float* __restrict__ partials, float* __restrict__ out,
    int off, int m0, int leaf, int isroot)
{
    const int m = blockIdx.x;
    const int j = threadIdx.x;
    const long g = (long)off + m0 + m;
    const bf16raw* Grow = G + (long)m * ldG;

    float iv = sigm(bf2f(Grow[j]));
    float ov = sigm(bf2f(Grow[128 + j]));
    float uv = tanhf(bf2f(Grow[256 + j]));
    float c = iv * uv;
    if (!leaf) {
        float f1 = sigm(bf2f(Grow[384 + j]));
        float f2 = sigm(bf2f(Grow[512 + j]));
        c += f1 * bf2f(c_all[(2 * g + 1) * 128 + j])
           + f2 * bf2f(c_all[(2 * g + 2) * 128 + j]);
    }
    float h = ov * tanhf(c);
    h_all[g * 128 + j] = f2bf(h);
    c_all[g * 128 + j] = f2bf(c);

    float p0 = h * Wout[j];
    float p1 = h * Wout[128 + j];
    float p2 = h * Wout[256 + j];
    float p3 = h * Wout[384 + j];
    float p4 = h * Wout[512 + j];
#pragma unroll
    for (int s = 32; s > 0; s >>= 1) {
        p0 += __shfl_down(p0, s);
        p1 += __shfl_down(p1, s);
        p2 += __shfl_down(p2, s);
        p3 += __shfl_down(p3, s);
        p4 += __shfl_down(p4, s);
    }
    __shared__ float red[2][5];
    if ((j & 63) == 0) {
        int wv = j >> 6;
        red[wv][0] = p0; red[wv][1] = p1; red[wv][2] = p2; red[wv][3] = p3; red[wv][4] = p4;
    }
    __syncthreads();
    if (j == 0) {
        float lg[5];
        float mx = -1e30f;
#pragma unroll
        for (int l = 0; l < 5; l++) {
            lg[l] = red[0][l] + red[1][l] + bout[l];
            mx = fmaxf(mx, lg[l]);
        }
        float se = 0.f;
#pragma unroll
        for (int l = 0; l < 5; l++) se += __expf(lg[l] - mx);
        float lse = __logf(se) + mx;
        int lab = labels[g];
        atomicAdd(&partials[m & 1023], lse - lg[lab]);
        if (isroot) {
#pragma unroll
            for (int l = 0; l < 5; l++) out[l] = lg[l] - lse;
        }
    }
}

__global__ __launch_bounds__(256) void k3_reduce(const float* __restrict__ partials,
                                                 float* __restrict__ out)
{
    const int t = threadIdx.x;
    float s = 0.f;
    for (int i = t; i < 1024; i += 256) s += partials[i];
#pragma unroll
    for (int d = 32; d > 0; d >>= 1) s += __shfl_down(s, d);
    __shared__ float red[4];
    if ((t & 63) == 0) red[t >> 6] = s;
    __syncthreads();
    if (t == 0) out[5] = red[0] + red[1] + red[2] + red[3];
}

// ---------------------------------------------------------------------------
extern "C" void kernel_launch(void* const* d_in, const int* in_sizes, int n_in,
                              void* d_out, int out_size, void* d_ws, size_t ws_size,
                              hipStream_t stream)
{
    const float* embeds = (const float*)d_in[0];
    const int* words = (const int*)d_in[1];
    const int* labels = (const int*)d_in[2];
    const float* Wix = (const float*)d_in[5],  *bix  = (const float*)d_in[6];
    const float* Wih = (const float*)d_in[7],  *bih  = (const float*)d_in[8];
    const float* Wfx = (const float*)d_in[9],  *bfx  = (const float*)d_in[10];
    const float* Wfh = (const float*)d_in[11], *bfh  = (const float*)d_in[12];
    const float* Wox = (const float*)d_in[13], *box_ = (const float*)d_in[14];
    const float* Woh = (const float*)d_in[15], *boh  = (const float*)d_in[16];
    const float* Wux = (const float*)d_in[17], *bux  = (const float*)d_in[18];
    const float* Wuh = (const float*)d_in[19], *buh  = (const float*)d_in[20];
    const float* Wout = (const float*)d_in[21], *bout = (const float*)d_in[22];
    float* out = (float*)d_out;

    // Workspace layout:
    //   h_all, c_all : NNODES*128 bf16 each        (134.2 MB)
    //   embeds_bf    : NVOCAB*128 bf16             (12.8 MB)
    //   BcatT        : 640*384 bf16                (0.49 MB)
    //   bias_cat     : 640 fp32 ; partials 1024 fp32
    //   G            : chunk*640 bf16              (adaptive)
    char* ws = (char*)d_ws;
    const size_t treeElems = (size_t)NNODES * 128;
    bf16raw* h_all = (bf16raw*)ws;
    bf16raw* c_all = h_all + treeElems;
    bf16raw* embeds_bf = c_all + treeElems;
    bf16raw* BcatT = embeds_bf + (size_t)NVOCAB * 128;
    float* bias_cat = (float*)(BcatT + 640 * 384);
    float* partials = bias_cat + 640;
    bf16raw* G = (bf16raw*)(partials + 1024);

    const size_t fixedBytes = (char*)G - ws;
    size_t avail = (ws_size > fixedBytes) ? (ws_size - fixedBytes) : 0;
    long cap = (long)(avail / (640 * sizeof(bf16raw)));
    int chunk = (int)((cap / 128) * 128);
    if (chunk < 128) chunk = 128;
    if (chunk > 131072) chunk = 131072;

    k_prep_embeds<<<(NVOCAB * 128 / 4 + 255) / 256, 256, 0, stream>>>(
        embeds, embeds_bf, NVOCAB * 128 / 4);
    k_prep_bcat<<<640, 128, 0, stream>>>(Wix, bix, Wih, bih, Wfx, bfx, Wfh, bfh,
                                         Wox, box_, Woh, boh, Wux, bux, Wuh, buh,
                                         BcatT, bias_cat);
    hipMemsetAsync(partials, 0, 1024 * sizeof(float), stream);

    for (int l = DEPTH - 1; l >= 0; --l) {
        const int n = 1 << l;
        const int off = n - 1;
        const int leaf = (l == DEPTH - 1) ? 1 : 0;
        const int S = leaf ? 384 : 640;
        const int Kc = leaf ? 128 : 384;
        const int ncb = S / 128;
        for (int m0 = 0; m0 < n; m0 += chunk) {
            const int nm = (n - m0 < chunk) ? (n - m0) : chunk;
            dim3 g1((nm + 127) / 128, ncb);
            k_gemm<<<g1, 256, 0, stream>>>(embeds_bf, words, h_all, BcatT, bias_cat,
                                           G, off, m0, nm, Kc, S);
            k_gates<<<nm, 128, 0, stream>>>(G, S, h_all, c_all, labels, Wout, bout,
                                            partials, out, off, m0, leaf, (l == 0) ? 1 : 0);
        }
    }
    k3_reduce<<<1, 256, 0, stream>>>(partials, out);
}